// Round 4
// baseline (403.559 us; speedup 1.0000x reference)
//
#include <hip/hip_runtime.h>
#include <math.h>

#define N_NODES 50000
#define N_EDGES 800000
#define E_TOT   (N_EDGES + N_NODES)   // 850000, self-loops appended
#define NEG_SLOPE 0.2f

// ---- workspace layout (bytes), 16-aligned ----
// padded CSR: 64 slots per node
#define CNT_OFF    0UL           // N u32 (zeroed)
#define ZERO_BYTES 200000UL
#define CSR_OFF    200000UL      // N*64 i32 = 12,800,000 -> 13,000,000
#define VS1_OFF    13000000UL    // 12 f32 (pad 64)
#define VD1_OFF    13000064UL    // 12 f32 (pad 64)
#define VAS2_OFF   13000128UL    // 256 f32 = 1024
#define VAD2_OFF   13001152UL    // 256 f32 = 1024
#define AS1_OFF    13002176UL    // N*4 f32 = 800,000
#define AD1_OFF    13802176UL    // N*4 f32
#define X2_OFF     14602176UL    // N*256 f32 = 51,200,000
#define H2_OFF     65802176UL    // N*64 f32 = 12,800,000
#define AS2_OFF    78602176UL    // N f32
#define AD2_OFF    78802176UL    // N f32 (end 79,002,176 < 80.8MB known-good)

__device__ __forceinline__ float wave_reduce_sum(float v) {
    #pragma unroll
    for (int off = 32; off > 0; off >>= 1) v += __shfl_xor(v, off, 64);
    return v;
}
__device__ __forceinline__ float wave_reduce_max(float v) {
    #pragma unroll
    for (int off = 32; off > 0; off >>= 1) v = fmaxf(v, __shfl_xor(v, off, 64));
    return v;
}
// reductions within a 16-lane group (xor<16 stays inside the group)
__device__ __forceinline__ float grp_reduce_sum(float v) {
    #pragma unroll
    for (int off = 8; off > 0; off >>= 1) v += __shfl_xor(v, off, 64);
    return v;
}
__device__ __forceinline__ float grp_reduce_max(float v) {
    #pragma unroll
    for (int off = 8; off > 0; off >>= 1) v = fmaxf(v, __shfl_xor(v, off, 64));
    return v;
}
__device__ __forceinline__ float lrelu(float v) { return v > 0.f ? v : NEG_SLOPE * v; }
__device__ __forceinline__ float elu(float v)   { return v > 0.f ? v : expf(v) - 1.f; }

// K0: all weight folds in one block.
// waves 0..3: vs1/vd1 (W1 folded through a_src1/a_dst1, 12 floats each)
// then thread k (0..255): vas2/vad2 (W2 folded through a_src2/a_dst2, 256 each)
__global__ void precompute_folds(const float* __restrict__ W1, const float* __restrict__ a_s1,
                                 const float* __restrict__ a_d1, const float* __restrict__ W2,
                                 const float* __restrict__ a_s2, const float* __restrict__ a_d2,
                                 float* __restrict__ vs1, float* __restrict__ vd1,
                                 float* __restrict__ vas2, float* __restrict__ vad2) {
    int t = threadIdx.x, h = t >> 6, lane = t & 63;
    float avs = a_s1[h*64 + lane], avd = a_d1[h*64 + lane];
    #pragma unroll
    for (int k = 0; k < 3; ++k) {
        float w = W1[k*256 + h*64 + lane];
        float ps = wave_reduce_sum(w * avs);
        float pd = wave_reduce_sum(w * avd);
        if (lane == 0) { vs1[k*4+h] = ps; vd1[k*4+h] = pd; }
    }
    int k = t;  // 256 threads, one W2 row each
    float ss = 0.f, dd = 0.f;
    for (int c = 0; c < 64; ++c) {
        float wv = W2[k*64 + c];
        ss = fmaf(wv, a_s2[c], ss);
        dd = fmaf(wv, a_d2[c], dd);
    }
    vas2[k] = ss; vad2[k] = dd;
}

// K1: per-node layer-1 alphas from folded vectors (24 FMAs per node).
__global__ void node_alpha1(const float* __restrict__ x, const float* __restrict__ vs,
                            const float* __restrict__ vd, float* __restrict__ as1,
                            float* __restrict__ ad1) {
    int n = blockIdx.x*blockDim.x + threadIdx.x;
    if (n >= N_NODES) return;
    float x0 = x[n*3+0], x1 = x[n*3+1], x2v = x[n*3+2];
    float4 s, d;
    s.x = x0*vs[0] + x1*vs[4] + x2v*vs[8];
    s.y = x0*vs[1] + x1*vs[5] + x2v*vs[9];
    s.z = x0*vs[2] + x1*vs[6] + x2v*vs[10];
    s.w = x0*vs[3] + x1*vs[7] + x2v*vs[11];
    d.x = x0*vd[0] + x1*vd[4] + x2v*vd[8];
    d.y = x0*vd[1] + x1*vd[5] + x2v*vd[9];
    d.z = x0*vd[2] + x1*vd[6] + x2v*vd[10];
    d.w = x0*vd[3] + x1*vd[7] + x2v*vd[11];
    *(float4*)(as1 + (size_t)n*4) = s;
    *(float4*)(ad1 + (size_t)n*4) = d;
}

// K2: build padded CSR in ONE pass. 8 edges/thread -> 8 outstanding atomics.
// slot count per node = 64 (Poisson(16)+1 degree; overflow clamped, prob ~0).
__global__ void build_csr(const int* __restrict__ ei, unsigned* __restrict__ cnt,
                          int* __restrict__ csr) {
    int tid = blockIdx.x*blockDim.x + threadIdx.x;
    int base = tid * 8;
    if (base >= E_TOT) return;           // E_TOT%8==0 -> clean per-thread ranges
    if (base < N_EDGES) {                // N_EDGES%8==0 -> no mixed threads
        int4 sa = *(const int4*)(ei + base);
        int4 sb = *(const int4*)(ei + base + 4);
        int4 da = *(const int4*)(ei + N_EDGES + base);
        int4 db = *(const int4*)(ei + N_EDGES + base + 4);
        int ss[8] = {sa.x,sa.y,sa.z,sa.w,sb.x,sb.y,sb.z,sb.w};
        int dd[8] = {da.x,da.y,da.z,da.w,db.x,db.y,db.z,db.w};
        #pragma unroll
        for (int i = 0; i < 8; ++i) {
            unsigned p = atomicAdd(&cnt[dd[i]], 1u);
            if (p < 64u) csr[((unsigned)dd[i] << 6) + p] = ss[i];
        }
    } else {                             // self-loops
        #pragma unroll
        for (int i = 0; i < 8; ++i) {
            int v = base + i - N_EDGES;
            unsigned p = atomicAdd(&cnt[v], 1u);
            if (p < 64u) csr[((unsigned)v << 6) + p] = v;
        }
    }
}

// K3: fused layer-1. 16 lanes/node, 4 nodes/wave, 16 nodes/block.
// Aggregation factored: g[h][k] = sum_e alpha_e^h * x[src_e][k] (12 floats),
// then x2[j] = elu(sum_k W1[k][j]*g[h][k] + b1[j]).
__global__ void gat1_node(const int* __restrict__ csr, const unsigned* __restrict__ cnt,
                          const float* __restrict__ x, const float* __restrict__ W1,
                          const float* __restrict__ as1, const float* __restrict__ ad1,
                          const float* __restrict__ b1, float* __restrict__ x2out) {
    int lane = threadIdx.x & 63, w = threadIdx.x >> 6;
    int subl = lane & 15, grp = lane >> 4;
    int n = blockIdx.x*16 + w*4 + grp;          // grid exact: 3125*16 = 50000
    unsigned deg = min(cnt[n], 64u);
    unsigned base = (unsigned)n << 6;
    float4 adv = *(const float4*)(ad1 + (size_t)n*4);
    // phase A: max per head
    float m0=-INFINITY, m1=-INFINITY, m2=-INFINITY, m3=-INFINITY;
    for (unsigned c = subl; c < deg; c += 16) {
        int s = csr[base + c];
        float4 as = *(const float4*)(as1 + (size_t)s*4);
        m0 = fmaxf(m0, lrelu(as.x+adv.x));
        m1 = fmaxf(m1, lrelu(as.y+adv.y));
        m2 = fmaxf(m2, lrelu(as.z+adv.z));
        m3 = fmaxf(m3, lrelu(as.w+adv.w));
    }
    m0 = grp_reduce_max(m0); m1 = grp_reduce_max(m1);
    m2 = grp_reduce_max(m2); m3 = grp_reduce_max(m3);
    // phase B: exp-sum per head
    float d0=0.f, d1=0.f, d2=0.f, d3=0.f;
    for (unsigned c = subl; c < deg; c += 16) {
        int s = csr[base + c];
        float4 as = *(const float4*)(as1 + (size_t)s*4);
        d0 += expf(lrelu(as.x+adv.x) - m0);
        d1 += expf(lrelu(as.y+adv.y) - m1);
        d2 += expf(lrelu(as.z+adv.z) - m2);
        d3 += expf(lrelu(as.w+adv.w) - m3);
    }
    float r_0 = 1.f/(grp_reduce_sum(d0) + 1e-16f);
    float r_1 = 1.f/(grp_reduce_sum(d1) + 1e-16f);
    float r_2 = 1.f/(grp_reduce_sum(d2) + 1e-16f);
    float r_3 = 1.f/(grp_reduce_sum(d3) + 1e-16f);
    // phase C: accumulate g[h][k]
    float g00=0,g01=0,g02=0, g10=0,g11=0,g12=0, g20=0,g21=0,g22=0, g30=0,g31=0,g32=0;
    for (unsigned c = subl; c < deg; c += 16) {
        int s = csr[base + c];
        float4 as = *(const float4*)(as1 + (size_t)s*4);
        float e0 = expf(lrelu(as.x+adv.x) - m0);
        float e1 = expf(lrelu(as.y+adv.y) - m1);
        float e2 = expf(lrelu(as.z+adv.z) - m2);
        float e3 = expf(lrelu(as.w+adv.w) - m3);
        float xa = x[s*3+0], xb = x[s*3+1], xc = x[s*3+2];
        g00 = fmaf(e0,xa,g00); g01 = fmaf(e0,xb,g01); g02 = fmaf(e0,xc,g02);
        g10 = fmaf(e1,xa,g10); g11 = fmaf(e1,xb,g11); g12 = fmaf(e1,xc,g12);
        g20 = fmaf(e2,xa,g20); g21 = fmaf(e2,xb,g21); g22 = fmaf(e2,xc,g22);
        g30 = fmaf(e3,xa,g30); g31 = fmaf(e3,xb,g31); g32 = fmaf(e3,xc,g32);
    }
    g00 = grp_reduce_sum(g00)*r_0; g01 = grp_reduce_sum(g01)*r_0; g02 = grp_reduce_sum(g02)*r_0;
    g10 = grp_reduce_sum(g10)*r_1; g11 = grp_reduce_sum(g11)*r_1; g12 = grp_reduce_sum(g12)*r_1;
    g20 = grp_reduce_sum(g20)*r_2; g21 = grp_reduce_sum(g21)*r_2; g22 = grp_reduce_sum(g22)*r_2;
    g30 = grp_reduce_sum(g30)*r_3; g31 = grp_reduce_sum(g31)*r_3; g32 = grp_reduce_sum(g32)*r_3;
    // epilogue: 256 channels across 16 lanes
    float* xrow = x2out + (size_t)n*256;
    #pragma unroll
    for (int i = 0; i < 16; ++i) {
        int j = i*16 + subl;
        float ga, gb, gc;
        if      (i < 4)  { ga=g00; gb=g01; gc=g02; }
        else if (i < 8)  { ga=g10; gb=g11; gc=g12; }
        else if (i < 12) { ga=g20; gb=g21; gc=g22; }
        else             { ga=g30; gb=g31; gc=g32; }
        float val = ga*W1[j] + gb*W1[256+j] + gc*W1[512+j] + b1[j];
        xrow[j] = elu(val);
    }
}

// K4: h2 = x2 @ W2 (256->64), lane = node, 32 channels per wave in registers.
// W2 row values are wave-uniform -> scalar loads; no LDS, no barriers.
// alpha_s2/ad2 folded through W2 (vas2/vad2), computed by half==0 in-loop.
__global__ __launch_bounds__(256) void node_prep2(
        const float* __restrict__ x2, const float* __restrict__ W2,
        const float* __restrict__ vas2, const float* __restrict__ vad2,
        float* __restrict__ h2, float* __restrict__ as2, float* __restrict__ ad2) {
    int t = threadIdx.x, w = t >> 6, lane = t & 63;
    int grp  = blockIdx.x*2 + (w >> 1);     // 64-node group
    int half = w & 1, c0 = half*32;
    int n = grp*64 + lane;
    bool valid = n < N_NODES;
    int nc = valid ? n : N_NODES-1;
    const float* xrow = x2 + (size_t)nc*256;
    float acc[32];
    #pragma unroll
    for (int c = 0; c < 32; ++c) acc[c] = 0.f;
    float pas = 0.f, pad = 0.f;
    for (int k0 = 0; k0 < 256; k0 += 16) {
        float4 xva = *(const float4*)(xrow + k0);
        float4 xvb = *(const float4*)(xrow + k0 + 4);
        float4 xvc = *(const float4*)(xrow + k0 + 8);
        float4 xvd = *(const float4*)(xrow + k0 + 12);
        float xv[16] = {xva.x,xva.y,xva.z,xva.w, xvb.x,xvb.y,xvb.z,xvb.w,
                        xvc.x,xvc.y,xvc.z,xvc.w, xvd.x,xvd.y,xvd.z,xvd.w};
        #pragma unroll
        for (int kk = 0; kk < 16; ++kk) {
            float xk = xv[kk];
            if (half == 0) {                      // wave-uniform branch
                pas = fmaf(xk, vas2[k0+kk], pas);
                pad = fmaf(xk, vad2[k0+kk], pad);
            }
            const float* wr = W2 + (k0+kk)*64 + c0;  // uniform -> s_load
            #pragma unroll
            for (int c = 0; c < 32; ++c)
                acc[c] = fmaf(xk, wr[c], acc[c]);
        }
    }
    if (valid) {
        float4* hp = (float4*)(h2 + (size_t)n*64 + c0);
        #pragma unroll
        for (int c = 0; c < 8; ++c)
            hp[c] = make_float4(acc[c*4], acc[c*4+1], acc[c*4+2], acc[c*4+3]);
        if (half == 0) { as2[n] = pas; ad2[n] = pad; }
    }
}

// K5: fused layer-2 + FC + sigmoid. One wave per node; deg<=64 so alpha
// phases are loop-free. Aggregation: lane = (edge-slot 0..15, quarter 0..3),
// acc[16] channels, 16-lane xor reduce over edge slots.
__global__ void gat2_node(const int* __restrict__ csr, const unsigned* __restrict__ cnt,
                          const float* __restrict__ h2, const float* __restrict__ as2,
                          const float* __restrict__ ad2, const float* __restrict__ b2,
                          const float* __restrict__ Wfc, const float* __restrict__ bfc,
                          float* __restrict__ out) {
    int lane = threadIdx.x & 63, w = threadIdx.x >> 6;
    int n = blockIdx.x*4 + w;               // grid exact: 12500*4 = 50000
    unsigned deg = min(cnt[n], 64u);
    unsigned base = (unsigned)n << 6;
    float adv = ad2[n];
    // alpha for edge = lane
    int s_l = 0; float e_l = -INFINITY;
    if (lane < (int)deg) { s_l = csr[base + lane]; e_l = lrelu(as2[s_l] + adv); }
    float m = wave_reduce_max(e_l);
    float ex_l = (lane < (int)deg) ? expf(e_l - m) : 0.f;
    float den = wave_reduce_sum(ex_l);
    float al_l = ex_l / (den + 1e-16f);
    // aggregation
    int eq = lane & 15, q = lane >> 4;
    float acc[16];
    #pragma unroll
    for (int j = 0; j < 16; ++j) acc[j] = 0.f;
    #pragma unroll
    for (int r = 0; r < 4; ++r) {
        int e = r*16 + eq;
        float al = __shfl(al_l, e, 64);
        int   s  = __shfl(s_l,  e, 64);
        if (e < (int)deg) {
            const float4* hp = (const float4*)(h2 + (size_t)s*64 + q*16);
            float4 h0 = hp[0], h1 = hp[1], h2v = hp[2], h3 = hp[3];
            acc[0]  = fmaf(h0.x, al, acc[0]);  acc[1]  = fmaf(h0.y, al, acc[1]);
            acc[2]  = fmaf(h0.z, al, acc[2]);  acc[3]  = fmaf(h0.w, al, acc[3]);
            acc[4]  = fmaf(h1.x, al, acc[4]);  acc[5]  = fmaf(h1.y, al, acc[5]);
            acc[6]  = fmaf(h1.z, al, acc[6]);  acc[7]  = fmaf(h1.w, al, acc[7]);
            acc[8]  = fmaf(h2v.x,al, acc[8]);  acc[9]  = fmaf(h2v.y,al, acc[9]);
            acc[10] = fmaf(h2v.z,al, acc[10]); acc[11] = fmaf(h2v.w,al, acc[11]);
            acc[12] = fmaf(h3.x, al, acc[12]); acc[13] = fmaf(h3.y, al, acc[13]);
            acc[14] = fmaf(h3.z, al, acc[14]); acc[15] = fmaf(h3.w, al, acc[15]);
        }
        if ((unsigned)(r*16 + 16) >= deg) break;   // wave-uniform
    }
    // reduce over the 16 edge slots (xor < 16 stays in q-group)
    #pragma unroll
    for (int off = 1; off < 16; off <<= 1) {
        #pragma unroll
        for (int j = 0; j < 16; ++j) acc[j] += __shfl_xor(acc[j], off, 64);
    }
    // epilogue: my quarter's 16 channels of elu+FC
    float part = 0.f;
    #pragma unroll
    for (int j = 0; j < 16; ++j) {
        int c = q*16 + j;
        part = fmaf(elu(acc[j] + b2[c]), Wfc[c], part);
    }
    part += __shfl_xor(part, 16, 64);
    part += __shfl_xor(part, 32, 64);
    if (lane == 0) out[n] = 1.f/(1.f + expf(-(part + bfc[0])));
}

extern "C" void kernel_launch(void* const* d_in, const int* in_sizes, int n_in,
                              void* d_out, int out_size, void* d_ws, size_t ws_size,
                              hipStream_t stream) {
    const float* x      = (const float*)d_in[0];
    const int*   ei     = (const int*)  d_in[1];
    const float* W1     = (const float*)d_in[2];
    const float* a_src1 = (const float*)d_in[3];
    const float* a_dst1 = (const float*)d_in[4];
    const float* b1     = (const float*)d_in[5];
    const float* W2     = (const float*)d_in[6];
    const float* a_src2 = (const float*)d_in[7];
    const float* a_dst2 = (const float*)d_in[8];
    const float* b2     = (const float*)d_in[9];
    const float* Wfc    = (const float*)d_in[10];
    const float* bfc    = (const float*)d_in[11];
    float* out = (float*)d_out;

    char* ws = (char*)d_ws;
    unsigned* cnt  = (unsigned*)(ws + CNT_OFF);
    int*      csr  = (int*)     (ws + CSR_OFF);
    float*    vs1  = (float*)   (ws + VS1_OFF);
    float*    vd1  = (float*)   (ws + VD1_OFF);
    float*    vas2 = (float*)   (ws + VAS2_OFF);
    float*    vad2 = (float*)   (ws + VAD2_OFF);
    float*    as1  = (float*)   (ws + AS1_OFF);
    float*    ad1  = (float*)   (ws + AD1_OFF);
    float*    x2   = (float*)   (ws + X2_OFF);
    float*    h2   = (float*)   (ws + H2_OFF);
    float*    as2  = (float*)   (ws + AS2_OFF);
    float*    ad2  = (float*)   (ws + AD2_OFF);

    hipMemsetAsync(d_ws, 0, ZERO_BYTES, stream);   // cnt only

    const int BLK = 256;
    precompute_folds<<<1, BLK, 0, stream>>>(W1, a_src1, a_dst1, W2, a_src2, a_dst2,
                                            vs1, vd1, vas2, vad2);
    node_alpha1 <<<(N_NODES + BLK - 1)/BLK, BLK, 0, stream>>>(x, vs1, vd1, as1, ad1);
    build_csr   <<<(E_TOT/8 + BLK - 1)/BLK, BLK, 0, stream>>>(ei, cnt, csr);
    gat1_node   <<<N_NODES/16, BLK, 0, stream>>>(csr, cnt, x, W1, as1, ad1, b1, x2);
    node_prep2  <<<(N_NODES + 127)/128, BLK, 0, stream>>>(x2, W2, vas2, vad2, h2, as2, ad2);
    gat2_node   <<<N_NODES/4, BLK, 0, stream>>>(csr, cnt, h2, as2, ad2, b2, Wfc, bfc, out);
}

// Round 5
// 177.124 us; speedup vs baseline: 2.2784x; 2.2784x over previous
//
#include <hip/hip_runtime.h>
#include <math.h>

#define N_NODES 50000
#define N_EDGES 800000
#define E_TOT   (N_EDGES + N_NODES)   // 850000, self-loops appended
#define NEG_SLOPE 0.2f

// ---- workspace layout (bytes), 16-aligned ----
// padded CSR: 64 slots per node
#define CNT_OFF    0UL           // N u32 (zeroed)
#define ZERO_BYTES 200000UL
#define CSR_OFF    200000UL      // N*64 i32 = 12,800,000 -> 13,000,000
#define VS1_OFF    13000000UL    // 12 f32 (pad 64)
#define VD1_OFF    13000064UL    // 12 f32 (pad 64)
#define AS1_OFF    13002176UL    // N*4 f32 = 800,000
#define AD1_OFF    13802176UL    // N*4 f32
#define X2_OFF     14602176UL    // N*256 f32 = 51,200,000
#define H2_OFF     65802176UL    // N*64 f32 = 12,800,000
#define AS2_OFF    78602176UL    // N f32
#define AD2_OFF    78802176UL    // N f32 (end 79,002,176)

__device__ __forceinline__ float wave_reduce_sum(float v) {
    #pragma unroll
    for (int off = 32; off > 0; off >>= 1) v += __shfl_xor(v, off, 64);
    return v;
}
__device__ __forceinline__ float wave_reduce_max(float v) {
    #pragma unroll
    for (int off = 32; off > 0; off >>= 1) v = fmaxf(v, __shfl_xor(v, off, 64));
    return v;
}
// reductions within a 16-lane group (xor<16 stays inside the group)
__device__ __forceinline__ float grp_reduce_sum(float v) {
    #pragma unroll
    for (int off = 8; off > 0; off >>= 1) v += __shfl_xor(v, off, 64);
    return v;
}
__device__ __forceinline__ float grp_reduce_max(float v) {
    #pragma unroll
    for (int off = 8; off > 0; off >>= 1) v = fmaxf(v, __shfl_xor(v, off, 64));
    return v;
}
__device__ __forceinline__ float lrelu(float v) { return v > 0.f ? v : NEG_SLOPE * v; }
__device__ __forceinline__ float elu(float v)   { return v > 0.f ? v : expf(v) - 1.f; }

// K0: fold W1 through a_src1/a_dst1: v[k][h] = sum_c W1[k][h*64+c]*a[h][c]. 1 block.
__global__ void precompute_folds(const float* __restrict__ W1, const float* __restrict__ a_s1,
                                 const float* __restrict__ a_d1,
                                 float* __restrict__ vs1, float* __restrict__ vd1) {
    int t = threadIdx.x, h = t >> 6, lane = t & 63;
    float avs = a_s1[h*64 + lane], avd = a_d1[h*64 + lane];
    #pragma unroll
    for (int k = 0; k < 3; ++k) {
        float w = W1[k*256 + h*64 + lane];
        float ps = wave_reduce_sum(w * avs);
        float pd = wave_reduce_sum(w * avd);
        if (lane == 0) { vs1[k*4+h] = ps; vd1[k*4+h] = pd; }
    }
}

// K1: per-node layer-1 alphas from folded vectors (24 FMAs per node).
__global__ void node_alpha1(const float* __restrict__ x, const float* __restrict__ vs,
                            const float* __restrict__ vd, float* __restrict__ as1,
                            float* __restrict__ ad1) {
    int n = blockIdx.x*blockDim.x + threadIdx.x;
    if (n >= N_NODES) return;
    float x0 = x[n*3+0], x1 = x[n*3+1], x2v = x[n*3+2];
    float4 s, d;
    s.x = x0*vs[0] + x1*vs[4] + x2v*vs[8];
    s.y = x0*vs[1] + x1*vs[5] + x2v*vs[9];
    s.z = x0*vs[2] + x1*vs[6] + x2v*vs[10];
    s.w = x0*vs[3] + x1*vs[7] + x2v*vs[11];
    d.x = x0*vd[0] + x1*vd[4] + x2v*vd[8];
    d.y = x0*vd[1] + x1*vd[5] + x2v*vd[9];
    d.z = x0*vd[2] + x1*vd[6] + x2v*vd[10];
    d.w = x0*vd[3] + x1*vd[7] + x2v*vd[11];
    *(float4*)(as1 + (size_t)n*4) = s;
    *(float4*)(ad1 + (size_t)n*4) = d;
}

// K2: build padded CSR in ONE pass. 8 edges/thread -> 8 outstanding atomics.
__global__ void build_csr(const int* __restrict__ ei, unsigned* __restrict__ cnt,
                          int* __restrict__ csr) {
    int tid = blockIdx.x*blockDim.x + threadIdx.x;
    int base = tid * 8;
    if (base >= E_TOT) return;
    if (base < N_EDGES) {
        int4 sa = *(const int4*)(ei + base);
        int4 sb = *(const int4*)(ei + base + 4);
        int4 da = *(const int4*)(ei + N_EDGES + base);
        int4 db = *(const int4*)(ei + N_EDGES + base + 4);
        int ss[8] = {sa.x,sa.y,sa.z,sa.w,sb.x,sb.y,sb.z,sb.w};
        int dd[8] = {da.x,da.y,da.z,da.w,db.x,db.y,db.z,db.w};
        #pragma unroll
        for (int i = 0; i < 8; ++i) {
            unsigned p = atomicAdd(&cnt[dd[i]], 1u);
            if (p < 64u) csr[((unsigned)dd[i] << 6) + p] = ss[i];
        }
    } else {
        #pragma unroll
        for (int i = 0; i < 8; ++i) {
            int v = base + i - N_EDGES;
            unsigned p = atomicAdd(&cnt[v], 1u);
            if (p < 64u) csr[((unsigned)v << 6) + p] = v;
        }
    }
}

// K3: fused layer-1. 16 lanes/node, 4 nodes/wave, 16 nodes/block.
__global__ void gat1_node(const int* __restrict__ csr, const unsigned* __restrict__ cnt,
                          const float* __restrict__ x, const float* __restrict__ W1,
                          const float* __restrict__ as1, const float* __restrict__ ad1,
                          const float* __restrict__ b1, float* __restrict__ x2out) {
    int lane = threadIdx.x & 63, w = threadIdx.x >> 6;
    int subl = lane & 15, grp = lane >> 4;
    int n = blockIdx.x*16 + w*4 + grp;          // grid exact: 3125*16 = 50000
    unsigned deg = min(cnt[n], 64u);
    unsigned base = (unsigned)n << 6;
    float4 adv = *(const float4*)(ad1 + (size_t)n*4);
    // phase A: max per head
    float m0=-INFINITY, m1=-INFINITY, m2=-INFINITY, m3=-INFINITY;
    for (unsigned c = subl; c < deg; c += 16) {
        int s = csr[base + c];
        float4 as = *(const float4*)(as1 + (size_t)s*4);
        m0 = fmaxf(m0, lrelu(as.x+adv.x));
        m1 = fmaxf(m1, lrelu(as.y+adv.y));
        m2 = fmaxf(m2, lrelu(as.z+adv.z));
        m3 = fmaxf(m3, lrelu(as.w+adv.w));
    }
    m0 = grp_reduce_max(m0); m1 = grp_reduce_max(m1);
    m2 = grp_reduce_max(m2); m3 = grp_reduce_max(m3);
    // phase B: exp-sum per head
    float d0=0.f, d1=0.f, d2=0.f, d3=0.f;
    for (unsigned c = subl; c < deg; c += 16) {
        int s = csr[base + c];
        float4 as = *(const float4*)(as1 + (size_t)s*4);
        d0 += expf(lrelu(as.x+adv.x) - m0);
        d1 += expf(lrelu(as.y+adv.y) - m1);
        d2 += expf(lrelu(as.z+adv.z) - m2);
        d3 += expf(lrelu(as.w+adv.w) - m3);
    }
    float r_0 = 1.f/(grp_reduce_sum(d0) + 1e-16f);
    float r_1 = 1.f/(grp_reduce_sum(d1) + 1e-16f);
    float r_2 = 1.f/(grp_reduce_sum(d2) + 1e-16f);
    float r_3 = 1.f/(grp_reduce_sum(d3) + 1e-16f);
    // phase C: accumulate g[h][k]
    float g00=0,g01=0,g02=0, g10=0,g11=0,g12=0, g20=0,g21=0,g22=0, g30=0,g31=0,g32=0;
    for (unsigned c = subl; c < deg; c += 16) {
        int s = csr[base + c];
        float4 as = *(const float4*)(as1 + (size_t)s*4);
        float e0 = expf(lrelu(as.x+adv.x) - m0);
        float e1 = expf(lrelu(as.y+adv.y) - m1);
        float e2 = expf(lrelu(as.z+adv.z) - m2);
        float e3 = expf(lrelu(as.w+adv.w) - m3);
        float xa = x[s*3+0], xb = x[s*3+1], xc = x[s*3+2];
        g00 = fmaf(e0,xa,g00); g01 = fmaf(e0,xb,g01); g02 = fmaf(e0,xc,g02);
        g10 = fmaf(e1,xa,g10); g11 = fmaf(e1,xb,g11); g12 = fmaf(e1,xc,g12);
        g20 = fmaf(e2,xa,g20); g21 = fmaf(e2,xb,g21); g22 = fmaf(e2,xc,g22);
        g30 = fmaf(e3,xa,g30); g31 = fmaf(e3,xb,g31); g32 = fmaf(e3,xc,g32);
    }
    g00 = grp_reduce_sum(g00)*r_0; g01 = grp_reduce_sum(g01)*r_0; g02 = grp_reduce_sum(g02)*r_0;
    g10 = grp_reduce_sum(g10)*r_1; g11 = grp_reduce_sum(g11)*r_1; g12 = grp_reduce_sum(g12)*r_1;
    g20 = grp_reduce_sum(g20)*r_2; g21 = grp_reduce_sum(g21)*r_2; g22 = grp_reduce_sum(g22)*r_2;
    g30 = grp_reduce_sum(g30)*r_3; g31 = grp_reduce_sum(g31)*r_3; g32 = grp_reduce_sum(g32)*r_3;
    float* xrow = x2out + (size_t)n*256;
    #pragma unroll
    for (int i = 0; i < 16; ++i) {
        int j = i*16 + subl;
        float ga, gb, gc;
        if      (i < 4)  { ga=g00; gb=g01; gc=g02; }
        else if (i < 8)  { ga=g10; gb=g11; gc=g12; }
        else if (i < 12) { ga=g20; gb=g21; gc=g22; }
        else             { ga=g30; gb=g31; gc=g32; }
        float val = ga*W1[j] + gb*W1[256+j] + gc*W1[512+j] + b1[j];
        xrow[j] = elu(val);
    }
}

// K4: h2 = x2 @ W2 (50000x256 @ 256x64) tiled GEMM.
// Block: 256 threads -> 64 nodes x 64 channels, 4x4 register tile/thread.
// K-tile 32: xT[32][68] (transposed, aligned rows), Wt[32][64]; 16.9 KB LDS.
#define KB 32
__global__ __launch_bounds__(256) void node_prep2(
        const float* __restrict__ x2, const float* __restrict__ W2,
        float* __restrict__ h2) {
    __shared__ float xT[KB][68];   // [k][node], stride 68 floats (16B-aligned rows)
    __shared__ float Wt[KB][64];   // [k][c]
    int t = threadIdx.x;
    int n0 = blockIdx.x * 64;
    int i = t & 15, j = t >> 4;    // node group 4i.., channel group 4j..
    float acc[4][4] = {{0,0,0,0},{0,0,0,0},{0,0,0,0},{0,0,0,0}};
    for (int k0 = 0; k0 < 256; k0 += KB) {
        __syncthreads();           // previous tile fully consumed
        // stage x2 tile (transpose): 64 nodes x 32 k = 512 float4, 2 rounds
        int p = t;
        #pragma unroll
        for (int rr = 0; rr < 2; ++rr, p += 256) {
            int node = p >> 3, c4 = p & 7;
            int nr = n0 + node; if (nr >= N_NODES) nr = N_NODES - 1;
            float4 v = *(const float4*)(x2 + (size_t)nr*256 + k0 + c4*4);
            xT[c4*4+0][node] = v.x;
            xT[c4*4+1][node] = v.y;
            xT[c4*4+2][node] = v.z;
            xT[c4*4+3][node] = v.w;
        }
        // stage W2 tile: 32 k x 64 c = 512 float4, 2 rounds (no transpose)
        p = t;
        #pragma unroll
        for (int rr = 0; rr < 2; ++rr, p += 256) {
            int kr = p >> 4, c4 = p & 15;
            *(float4*)(&Wt[kr][c4*4]) = *(const float4*)(W2 + (size_t)(k0+kr)*64 + c4*4);
        }
        __syncthreads();
        #pragma unroll
        for (int k = 0; k < KB; ++k) {
            float4 xv = *(const float4*)(&xT[k][4*i]);
            float4 wv = *(const float4*)(&Wt[k][4*j]);
            acc[0][0]=fmaf(xv.x,wv.x,acc[0][0]); acc[0][1]=fmaf(xv.x,wv.y,acc[0][1]);
            acc[0][2]=fmaf(xv.x,wv.z,acc[0][2]); acc[0][3]=fmaf(xv.x,wv.w,acc[0][3]);
            acc[1][0]=fmaf(xv.y,wv.x,acc[1][0]); acc[1][1]=fmaf(xv.y,wv.y,acc[1][1]);
            acc[1][2]=fmaf(xv.y,wv.z,acc[1][2]); acc[1][3]=fmaf(xv.y,wv.w,acc[1][3]);
            acc[2][0]=fmaf(xv.z,wv.x,acc[2][0]); acc[2][1]=fmaf(xv.z,wv.y,acc[2][1]);
            acc[2][2]=fmaf(xv.z,wv.z,acc[2][2]); acc[2][3]=fmaf(xv.z,wv.w,acc[2][3]);
            acc[3][0]=fmaf(xv.w,wv.x,acc[3][0]); acc[3][1]=fmaf(xv.w,wv.y,acc[3][1]);
            acc[3][2]=fmaf(xv.w,wv.z,acc[3][2]); acc[3][3]=fmaf(xv.w,wv.w,acc[3][3]);
        }
    }
    #pragma unroll
    for (int ii = 0; ii < 4; ++ii) {
        int n = n0 + 4*i + ii;
        if (n < N_NODES)
            *(float4*)(h2 + (size_t)n*64 + 4*j) =
                make_float4(acc[ii][0], acc[ii][1], acc[ii][2], acc[ii][3]);
    }
}

// K4b: as2/ad2 = h2 . a_src2 / a_dst2. One wave per node.
__global__ void node_alpha2(const float* __restrict__ h2, const float* __restrict__ a_s2,
                            const float* __restrict__ a_d2, float* __restrict__ as2,
                            float* __restrict__ ad2) {
    int lane = threadIdx.x & 63, w = threadIdx.x >> 6;
    int n = blockIdx.x*4 + w;      // grid exact: 12500*4 = 50000
    float v = h2[(size_t)n*64 + lane];
    float ps = wave_reduce_sum(v * a_s2[lane]);
    float pd = wave_reduce_sum(v * a_d2[lane]);
    if (lane == 0) { as2[n] = ps; ad2[n] = pd; }
}

// K5: fused layer-2 + FC + sigmoid. One wave per node; deg<=64 loop-free alphas.
__global__ void gat2_node(const int* __restrict__ csr, const unsigned* __restrict__ cnt,
                          const float* __restrict__ h2, const float* __restrict__ as2,
                          const float* __restrict__ ad2, const float* __restrict__ b2,
                          const float* __restrict__ Wfc, const float* __restrict__ bfc,
                          float* __restrict__ out) {
    int lane = threadIdx.x & 63, w = threadIdx.x >> 6;
    int n = blockIdx.x*4 + w;               // grid exact: 12500*4 = 50000
    unsigned deg = min(cnt[n], 64u);
    unsigned base = (unsigned)n << 6;
    float adv = ad2[n];
    int s_l = 0; float e_l = -INFINITY;
    if (lane < (int)deg) { s_l = csr[base + lane]; e_l = lrelu(as2[s_l] + adv); }
    float m = wave_reduce_max(e_l);
    float ex_l = (lane < (int)deg) ? expf(e_l - m) : 0.f;
    float den = wave_reduce_sum(ex_l);
    float al_l = ex_l / (den + 1e-16f);
    int eq = lane & 15, q = lane >> 4;
    float acc[16];
    #pragma unroll
    for (int j = 0; j < 16; ++j) acc[j] = 0.f;
    #pragma unroll
    for (int r = 0; r < 4; ++r) {
        int e = r*16 + eq;
        float al = __shfl(al_l, e, 64);
        int   s  = __shfl(s_l,  e, 64);
        if (e < (int)deg) {
            const float4* hp = (const float4*)(h2 + (size_t)s*64 + q*16);
            float4 h0 = hp[0], h1 = hp[1], h2v = hp[2], h3 = hp[3];
            acc[0]  = fmaf(h0.x, al, acc[0]);  acc[1]  = fmaf(h0.y, al, acc[1]);
            acc[2]  = fmaf(h0.z, al, acc[2]);  acc[3]  = fmaf(h0.w, al, acc[3]);
            acc[4]  = fmaf(h1.x, al, acc[4]);  acc[5]  = fmaf(h1.y, al, acc[5]);
            acc[6]  = fmaf(h1.z, al, acc[6]);  acc[7]  = fmaf(h1.w, al, acc[7]);
            acc[8]  = fmaf(h2v.x,al, acc[8]);  acc[9]  = fmaf(h2v.y,al, acc[9]);
            acc[10] = fmaf(h2v.z,al, acc[10]); acc[11] = fmaf(h2v.w,al, acc[11]);
            acc[12] = fmaf(h3.x, al, acc[12]); acc[13] = fmaf(h3.y, al, acc[13]);
            acc[14] = fmaf(h3.z, al, acc[14]); acc[15] = fmaf(h3.w, al, acc[15]);
        }
        if ((unsigned)(r*16 + 16) >= deg) break;   // wave-uniform
    }
    #pragma unroll
    for (int off = 1; off < 16; off <<= 1) {
        #pragma unroll
        for (int j = 0; j < 16; ++j) acc[j] += __shfl_xor(acc[j], off, 64);
    }
    float part = 0.f;
    #pragma unroll
    for (int j = 0; j < 16; ++j) {
        int c = q*16 + j;
        part = fmaf(elu(acc[j] + b2[c]), Wfc[c], part);
    }
    part += __shfl_xor(part, 16, 64);
    part += __shfl_xor(part, 32, 64);
    if (lane == 0) out[n] = 1.f/(1.f + expf(-(part + bfc[0])));
}

extern "C" void kernel_launch(void* const* d_in, const int* in_sizes, int n_in,
                              void* d_out, int out_size, void* d_ws, size_t ws_size,
                              hipStream_t stream) {
    const float* x      = (const float*)d_in[0];
    const int*   ei     = (const int*)  d_in[1];
    const float* W1     = (const float*)d_in[2];
    const float* a_src1 = (const float*)d_in[3];
    const float* a_dst1 = (const float*)d_in[4];
    const float* b1     = (const float*)d_in[5];
    const float* W2     = (const float*)d_in[6];
    const float* a_src2 = (const float*)d_in[7];
    const float* a_dst2 = (const float*)d_in[8];
    const float* b2     = (const float*)d_in[9];
    const float* Wfc    = (const float*)d_in[10];
    const float* bfc    = (const float*)d_in[11];
    float* out = (float*)d_out;

    char* ws = (char*)d_ws;
    unsigned* cnt  = (unsigned*)(ws + CNT_OFF);
    int*      csr  = (int*)     (ws + CSR_OFF);
    float*    vs1  = (float*)   (ws + VS1_OFF);
    float*    vd1  = (float*)   (ws + VD1_OFF);
    float*    as1  = (float*)   (ws + AS1_OFF);
    float*    ad1  = (float*)   (ws + AD1_OFF);
    float*    x2   = (float*)   (ws + X2_OFF);
    float*    h2   = (float*)   (ws + H2_OFF);
    float*    as2  = (float*)   (ws + AS2_OFF);
    float*    ad2  = (float*)   (ws + AD2_OFF);

    hipMemsetAsync(d_ws, 0, ZERO_BYTES, stream);   // cnt only

    const int BLK = 256;
    precompute_folds<<<1, BLK, 0, stream>>>(W1, a_src1, a_dst1, vs1, vd1);
    node_alpha1 <<<(N_NODES + BLK - 1)/BLK, BLK, 0, stream>>>(x, vs1, vd1, as1, ad1);
    build_csr   <<<(E_TOT/8 + BLK - 1)/BLK, BLK, 0, stream>>>(ei, cnt, csr);
    gat1_node   <<<N_NODES/16, BLK, 0, stream>>>(csr, cnt, x, W1, as1, ad1, b1, x2);
    node_prep2  <<<(N_NODES + 63)/64, BLK, 0, stream>>>(x2, W2, h2);
    node_alpha2 <<<N_NODES/4, BLK, 0, stream>>>(h2, a_src2, a_dst2, as2, ad2);
    gat2_node   <<<N_NODES/4, BLK, 0, stream>>>(csr, cnt, h2, as2, ad2, b2, Wfc, bfc, out);
}